// Round 1
// baseline (252.696 us; speedup 1.0000x reference)
//
#include <hip/hip_runtime.h>

// SpectralRewiringLayer: edge scorer MLP over 2M edges.
// Factorization: h1 = relu(u[src] + v[dst]) where
//   u[n] = W1[0:64]^T emb[n] + fied[n]*W1[128] + b1   (b1 folded into u)
//   v[n] = W1[64:128]^T emb[n] + fied[n]*W1[129]
// Kernel 1 precomputes u,v (fp32 math, bf16 storage, 25.6 MB in d_ws).
// Kernel 2: per 16-edge tile per wave: gather u/v rows, relu-add -> bf16 A frags,
//   layer2 via mfma_f32_16x16x32_bf16 (W2 B-frags preloaded in regs),
//   layer3 dot via per-lane partials + shfl_xor reduction over 16-lane groups.

#define HD 64

typedef __attribute__((ext_vector_type(8))) short short8;   // 8 bf16 = 4 VGPRs
typedef __attribute__((ext_vector_type(4))) float f32x4;

__device__ __forceinline__ float bf2f(unsigned int bits16) {
    union { unsigned int u; float f; } t; t.u = bits16 << 16; return t.f;
}
__device__ __forceinline__ unsigned short f2bf(float f) {
    union { float f; unsigned int u; } t; t.f = f;
    unsigned int r = t.u + 0x7fffu + ((t.u >> 16) & 1u);  // RNE
    return (unsigned short)(r >> 16);
}

// ---------------- Kernel 1: per-node precompute of u, v ----------------
// One wave handles 16 nodes; lane j computes output feature j.
// emb row values broadcast across the wave with __shfl (ds_bpermute).
__global__ __launch_bounds__(256) void precompute_uv(
    const float* __restrict__ emb, const float* __restrict__ fied,
    const float* __restrict__ W1, const float* __restrict__ b1,
    unsigned short* __restrict__ u, unsigned short* __restrict__ v,
    int n_nodes)
{
    const int lane = threadIdx.x & 63;
    const int wid  = blockIdx.x * (blockDim.x >> 6) + (threadIdx.x >> 6);
    const int n0 = wid * 16;
    if (n0 >= n_nodes) return;

    float e[16];
    #pragma unroll
    for (int i = 0; i < 16; ++i) {
        int n = n0 + i;
        e[i] = (n < n_nodes) ? emb[(size_t)n * HD + lane] : 0.f;
    }
    float au[16], av[16];
    #pragma unroll
    for (int i = 0; i < 16; ++i) { au[i] = 0.f; av[i] = 0.f; }

    for (int k = 0; k < HD; ++k) {
        float w1u = W1[k * HD + lane];          // coalesced, L1-resident
        float w1v = W1[(HD + k) * HD + lane];
        #pragma unroll
        for (int i = 0; i < 16; ++i) {
            float ek = __shfl(e[i], k, 64);
            au[i] = fmaf(ek, w1u, au[i]);
            av[i] = fmaf(ek, w1v, av[i]);
        }
    }
    const float w128 = W1[128 * HD + lane];
    const float w129 = W1[129 * HD + lane];
    const float bb   = b1[lane];
    #pragma unroll
    for (int i = 0; i < 16; ++i) {
        int n = n0 + i;
        if (n < n_nodes) {
            float f  = fied[n];
            float uu = au[i] + bb + f * w128;
            float vv = av[i] + f * w129;
            u[(size_t)n * HD + lane] = f2bf(uu);
            v[(size_t)n * HD + lane] = f2bf(vv);
        }
    }
}

// ---------------- Kernel 2: per-edge MLP (layers 2 + 3) ----------------
// One wave per 16-edge tile (grid-stride). MFMA 16x16x32 bf16 layouts
// (verified m89/m91/m120):
//   A[m][k]:   m = lane&15, k = (lane>>4)*8 + j   (+32 per K-step)
//   B[k][n]:   n = lane&15, k = (lane>>4)*8 + j
//   C/D[r][c]: c = lane&15, r = (lane>>4)*4 + reg
__global__ __launch_bounds__(256) void edge_mlp(
    const unsigned short* __restrict__ u, const unsigned short* __restrict__ v,
    const int* __restrict__ src, const int* __restrict__ dst,
    const float* __restrict__ W2, const float* __restrict__ b2,
    const float* __restrict__ W3, const float* __restrict__ b3,
    float* __restrict__ out, int E, int ntiles)
{
    const int lane = threadIdx.x & 63;
    const int q = lane >> 4;       // K-chunk / row-group selector
    const int c = lane & 15;       // edge-within-tile (A) & col (B, C/D)
    const int wid    = blockIdx.x * (blockDim.x >> 6) + (threadIdx.x >> 6);
    const int nwaves = gridDim.x * (blockDim.x >> 6);

    // Preload W2 B-fragments (per-wave constant), biases, W3 column.
    short8 Bf[4][2];
    #pragma unroll
    for (int t = 0; t < 4; ++t) {
        #pragma unroll
        for (int ks = 0; ks < 2; ++ks) {
            #pragma unroll
            for (int j = 0; j < 8; ++j) {
                int k = ks * 32 + q * 8 + j;
                Bf[t][ks][j] = (short)f2bf(W2[k * HD + t * 16 + c]);
            }
        }
    }
    float b2r[4], w3r[4];
    #pragma unroll
    for (int t = 0; t < 4; ++t) { b2r[t] = b2[t * 16 + c]; w3r[t] = W3[t * 16 + c]; }
    const float b3v = b3[0];

    for (int tile = wid; tile < ntiles; tile += nwaves) {
        const int e0 = tile * 16;
        const int e  = e0 + c;
        const bool val = (e < E);
        const int s = val ? src[e] : 0;
        const int d = val ? dst[e] : 0;

        // h1 = relu(u[s] + v[d]) -> bf16 A fragments (this lane's K slice).
        short8 A[2];
        #pragma unroll
        for (int ks = 0; ks < 2; ++ks) {
            const uint4 U = *(const uint4*)(u + (size_t)s * HD + ks * 32 + q * 8);
            const uint4 V = *(const uint4*)(v + (size_t)d * HD + ks * 32 + q * 8);
            unsigned int uw[4] = {U.x, U.y, U.z, U.w};
            unsigned int vw[4] = {V.x, V.y, V.z, V.w};
            #pragma unroll
            for (int w = 0; w < 4; ++w) {
                float a0 = bf2f(uw[w] & 0xffffu) + bf2f(vw[w] & 0xffffu);
                float a1 = bf2f(uw[w] >> 16)    + bf2f(vw[w] >> 16);
                a0 = fmaxf(a0, 0.f);
                a1 = fmaxf(a1, 0.f);
                A[ks][2 * w]     = (short)f2bf(a0);
                A[ks][2 * w + 1] = (short)f2bf(a1);
            }
        }

        // Layer 2 (MFMA over 4 N-tiles x 2 K-steps) fused with layer-3 partials.
        float p0 = 0.f, p1 = 0.f, p2 = 0.f, p3 = 0.f;
        #pragma unroll
        for (int t = 0; t < 4; ++t) {
            f32x4 acc = {0.f, 0.f, 0.f, 0.f};
            acc = __builtin_amdgcn_mfma_f32_16x16x32_bf16(A[0], Bf[t][0], acc, 0, 0, 0);
            acc = __builtin_amdgcn_mfma_f32_16x16x32_bf16(A[1], Bf[t][1], acc, 0, 0, 0);
            p0 += fmaxf(acc[0] + b2r[t], 0.f) * w3r[t];
            p1 += fmaxf(acc[1] + b2r[t], 0.f) * w3r[t];
            p2 += fmaxf(acc[2] + b2r[t], 0.f) * w3r[t];
            p3 += fmaxf(acc[3] + b2r[t], 0.f) * w3r[t];
        }
        // Reduce over the 16 lanes (c dim) of each q-group.
        #pragma unroll
        for (int m = 1; m < 16; m <<= 1) {
            p0 += __shfl_xor(p0, m, 64);
            p1 += __shfl_xor(p1, m, 64);
            p2 += __shfl_xor(p2, m, 64);
            p3 += __shfl_xor(p3, m, 64);
        }
        if (c == 0) {
            const int r0 = e0 + q * 4;
            float res[4] = {p0 + b3v, p1 + b3v, p2 + b3v, p3 + b3v};
            #pragma unroll
            for (int r = 0; r < 4; ++r)
                if (r0 + r < E) out[r0 + r] = res[r];
        }
    }
}

extern "C" void kernel_launch(void* const* d_in, const int* in_sizes, int n_in,
                              void* d_out, int out_size, void* d_ws, size_t ws_size,
                              hipStream_t stream) {
    const float* emb  = (const float*)d_in[0];
    const float* fied = (const float*)d_in[1];
    const float* W1   = (const float*)d_in[2];
    const float* b1   = (const float*)d_in[3];
    const float* W2   = (const float*)d_in[4];
    const float* b2   = (const float*)d_in[5];
    const float* W3   = (const float*)d_in[6];
    const float* b3   = (const float*)d_in[7];
    const int*   eidx = (const int*)d_in[8];

    const int n_nodes = in_sizes[1];          // fiedler length
    const int E       = in_sizes[8] / 2;      // edge_index is [2, E]
    const int* srcp = eidx;
    const int* dstp = eidx + E;

    unsigned short* u = (unsigned short*)d_ws;             // n_nodes*64 bf16
    unsigned short* v = u + (size_t)n_nodes * HD;          // n_nodes*64 bf16

    const int nwaves_pre = (n_nodes + 15) / 16;
    const int blocks_pre = (nwaves_pre + 3) / 4;
    precompute_uv<<<blocks_pre, 256, 0, stream>>>(emb, fied, W1, b1, u, v, n_nodes);

    const int ntiles = (E + 15) / 16;
    edge_mlp<<<2048, 256, 0, stream>>>(u, v, srcp, dstp, W2, b2, W3, b3,
                                       (float*)d_out, E, ntiles);
}

// Round 2
// 206.769 us; speedup vs baseline: 1.2221x; 1.2221x over previous
//
#include <hip/hip_runtime.h>

// SpectralRewiringLayer. Factorized: h1 = relu(u[src] + v[dst]),
//   u[n] = W1[0:64]^T emb[n] + b1 + fied[n]*W1[128]
//   v[n] = W1[64:128]^T emb[n] + fied[n]*W1[129]
// All intermediate storage fp16 (packed v_pk_add_f16 path, mfma *_f16).
// K1: u,v via MFMA GEMM (emb. W1), fp16 out in d_ws (25.6 MB).
// K2: per 16-edge tile/wave: gather half8 rows, pk-add+int-relu -> B frags,
//     h2^T = W2^T.h1^T via mfma (A=W2^T preloaded), fused layer-3 dot,
//     2-hop shfl_xor reduce, coalesced store.

#define HD 64

typedef __attribute__((ext_vector_type(8))) _Float16 half8;
typedef __attribute__((ext_vector_type(8))) short  short8;
typedef __attribute__((ext_vector_type(8))) float  float8;
typedef __attribute__((ext_vector_type(4))) float  f32x4;

__device__ __forceinline__ half8 relu_h8(half8 x) {
    // relu via sign-mask: negatives (incl -0) -> 0. Pure int vector ops.
    short8 b = __builtin_bit_cast(short8, x);
    short8 m = b >> 15;
    b = b & ~m;
    return __builtin_bit_cast(half8, b);
}

// ---------------- K1: u,v precompute as MFMA GEMM ----------------
// Per 16-node tile: A = emb rows (fp32->fp16), B = W1 cols (8 N-tiles:
// 4 for u [rows 0..63], 4 for v [rows 64..127]). D rows = nodes, cols = feat.
__global__ __launch_bounds__(256) void precompute_uv(
    const float* __restrict__ emb, const float* __restrict__ fied,
    const float* __restrict__ W1, const float* __restrict__ b1,
    _Float16* __restrict__ u, _Float16* __restrict__ v,
    int n_nodes, int ntiles)
{
    const int lane = threadIdx.x & 63;
    const int q = lane >> 4;
    const int c = lane & 15;
    const int wid = blockIdx.x * (blockDim.x >> 6) + (threadIdx.x >> 6);
    const int nw  = gridDim.x * (blockDim.x >> 6);

    // B-frags: B[k][n]: n = c (= feature col within tile), k = q*8+j+32*ks
    half8 Bf[8][2];
    #pragma unroll
    for (int t = 0; t < 8; ++t)
        #pragma unroll
        for (int ks = 0; ks < 2; ++ks)
            #pragma unroll
            for (int j = 0; j < 8; ++j) {
                int k = q * 8 + j + 32 * ks;
                int row = (t < 4) ? k : (64 + k);
                Bf[t][ks][j] = (_Float16)W1[row * HD + (t & 3) * 16 + c];
            }
    float b1f[4], wsf[4], wdf[4];
    #pragma unroll
    for (int t = 0; t < 4; ++t) {
        b1f[t] = b1[t * 16 + c];
        wsf[t] = W1[128 * HD + t * 16 + c];
        wdf[t] = W1[129 * HD + t * 16 + c];
    }

    for (int tile = wid; tile < ntiles; tile += nw) {
        const int n0 = tile * 16;
        int na = n0 + c;                       // A row this lane stages
        if (na >= n_nodes) na = n_nodes - 1;   // tail clamp (stores guarded)
        const float* rp = emb + (size_t)na * HD + q * 8;
        float8 a0 = *(const float8*)rp;         // k = q*8 .. q*8+7
        float8 a1 = *(const float8*)(rp + 32);  // k = 32+q*8 ..
        half8 A0 = __builtin_convertvector(a0, half8);
        half8 A1 = __builtin_convertvector(a1, half8);

        f32x4 aU[4] = {}, aV[4] = {};
        #pragma unroll
        for (int t = 0; t < 4; ++t) {
            aU[t] = __builtin_amdgcn_mfma_f32_16x16x32_f16(A0, Bf[t][0],     aU[t], 0, 0, 0);
            aU[t] = __builtin_amdgcn_mfma_f32_16x16x32_f16(A1, Bf[t][1],     aU[t], 0, 0, 0);
            aV[t] = __builtin_amdgcn_mfma_f32_16x16x32_f16(A0, Bf[4 + t][0], aV[t], 0, 0, 0);
            aV[t] = __builtin_amdgcn_mfma_f32_16x16x32_f16(A1, Bf[4 + t][1], aV[t], 0, 0, 0);
        }

        float fv[4];
        #pragma unroll
        for (int r = 0; r < 4; ++r) {
            int n = n0 + q * 4 + r;
            fv[r] = (n < n_nodes) ? fied[n] : 0.f;
        }
        // D layout: col = c (feature t*16+c), row = q*4+r (node n0+q*4+r)
        #pragma unroll
        for (int t = 0; t < 4; ++t)
            #pragma unroll
            for (int r = 0; r < 4; ++r) {
                int n = n0 + q * 4 + r;
                if (n < n_nodes) {
                    u[(size_t)n * HD + t * 16 + c] =
                        (_Float16)(aU[t][r] + b1f[t] + fv[r] * wsf[t]);
                    v[(size_t)n * HD + t * 16 + c] =
                        (_Float16)(aV[t][r] + fv[r] * wdf[t]);
                }
            }
    }
}

// ---------------- K2: per-edge MLP (layers 2+3), transposed product ------
// D' = W2^T . h1^T : A = W2^T (preloaded), B = h1^T (gathered fragments).
// D' layout: col = c = edge, row = q*4+r = feature t*16+q*4+r.
__global__ __launch_bounds__(256) void edge_mlp(
    const _Float16* __restrict__ u, const _Float16* __restrict__ v,
    const int* __restrict__ src, const int* __restrict__ dst,
    const float* __restrict__ W2, const float* __restrict__ b2,
    const float* __restrict__ W3, const float* __restrict__ b3,
    float* __restrict__ out, int E, int ntiles)
{
    const int lane = threadIdx.x & 63;
    const int q = lane >> 4;
    const int c = lane & 15;
    const int wid = blockIdx.x * (blockDim.x >> 6) + (threadIdx.x >> 6);
    const int nw  = gridDim.x * (blockDim.x >> 6);

    // A-frags: A[m][k], m = c -> out-feature t*16+c, k = q*8+j+32*ks:
    //   value = W2^T[t*16+c][k] = W2[k*64 + t*16 + c]
    half8 Af[4][2];
    #pragma unroll
    for (int t = 0; t < 4; ++t)
        #pragma unroll
        for (int ks = 0; ks < 2; ++ks)
            #pragma unroll
            for (int j = 0; j < 8; ++j) {
                int k = q * 8 + j + 32 * ks;
                Af[t][ks][j] = (_Float16)W2[k * HD + t * 16 + c];
            }
    // epilogue consts for feature f = t*16 + q*4 + r (this lane's D rows)
    float b2q[4][4], w3q[4][4];
    #pragma unroll
    for (int t = 0; t < 4; ++t)
        #pragma unroll
        for (int r = 0; r < 4; ++r) {
            int f = t * 16 + q * 4 + r;
            b2q[t][r] = b2[f];
            w3q[t][r] = W3[f];
        }
    const float b3v = b3[0];

    int tile = wid;
    half8 Ua, Ub, Va, Vb;
    if (tile < ntiles) {
        int e = tile * 16 + c; if (e >= E) e = E - 1;
        const int s = src[e], d = dst[e];
        const half8* up = (const half8*)(u + (unsigned)s * HD + q * 8);
        const half8* vp = (const half8*)(v + (unsigned)d * HD + q * 8);
        Ua = up[0]; Ub = up[4]; Va = vp[0]; Vb = vp[4];
    }

    for (; tile < ntiles; tile += nw) {
        const int nt = tile + nw;
        int sn = 0, dn = 0;
        if (nt < ntiles) {                       // prefetch next indices
            int e2 = nt * 16 + c; if (e2 >= E) e2 = E - 1;
            sn = src[e2]; dn = dst[e2];
        }
        // h1 fragments (consume current gathers): pk_add + int-relu, no cvt
        half8 B0 = relu_h8(Ua + Va);
        half8 B1 = relu_h8(Ub + Vb);
        if (nt < ntiles) {                       // issue next gathers early
            const half8* up = (const half8*)(u + (unsigned)sn * HD + q * 8);
            const half8* vp = (const half8*)(v + (unsigned)dn * HD + q * 8);
            Ua = up[0]; Ub = up[4]; Va = vp[0]; Vb = vp[4];
        }

        f32x4 acc[4] = {};
        #pragma unroll
        for (int t = 0; t < 4; ++t) {
            acc[t] = __builtin_amdgcn_mfma_f32_16x16x32_f16(Af[t][0], B0, acc[t], 0, 0, 0);
            acc[t] = __builtin_amdgcn_mfma_f32_16x16x32_f16(Af[t][1], B1, acc[t], 0, 0, 0);
        }

        // layer 3: p = sum_f relu(h2_f + b2_f) * w3_f over this lane's rows
        float p = 0.f;
        #pragma unroll
        for (int t = 0; t < 4; ++t)
            #pragma unroll
            for (int r = 0; r < 4; ++r)
                p = fmaf(fmaxf(acc[t][r] + b2q[t][r], 0.f), w3q[t][r], p);
        // reduce across the 4 q-groups holding the same edge c
        p += __shfl_xor(p, 16, 64);
        p += __shfl_xor(p, 32, 64);
        if (q == 0) {
            int e = tile * 16 + c;
            if (e < E) out[e] = p + b3v;
        }
    }
}

extern "C" void kernel_launch(void* const* d_in, const int* in_sizes, int n_in,
                              void* d_out, int out_size, void* d_ws, size_t ws_size,
                              hipStream_t stream) {
    const float* emb  = (const float*)d_in[0];
    const float* fied = (const float*)d_in[1];
    const float* W1   = (const float*)d_in[2];
    const float* b1   = (const float*)d_in[3];
    const float* W2   = (const float*)d_in[4];
    const float* b2   = (const float*)d_in[5];
    const float* W3   = (const float*)d_in[6];
    const float* b3   = (const float*)d_in[7];
    const int*   eidx = (const int*)d_in[8];

    const int n_nodes = in_sizes[1];
    const int E       = in_sizes[8] / 2;
    const int* srcp = eidx;
    const int* dstp = eidx + E;

    _Float16* u = (_Float16*)d_ws;                 // n_nodes*64 fp16
    _Float16* v = u + (size_t)n_nodes * HD;        // n_nodes*64 fp16

    const int ntilesN = (n_nodes + 15) / 16;
    precompute_uv<<<512, 256, 0, stream>>>(emb, fied, W1, b1, u, v,
                                           n_nodes, ntilesN);

    const int ntilesE = (E + 15) / 16;
    edge_mlp<<<1024, 256, 0, stream>>>(u, v, srcp, dstp, W2, b2, W3, b3,
                                       (float*)d_out, E, ntilesE);
}

// Round 3
// 181.778 us; speedup vs baseline: 1.3901x; 1.1375x over previous
//
#include <hip/hip_runtime.h>

// SpectralRewiringLayer. Factorized: h1 = relu(u[src] + v[dst]),
//   u[n] = W1[0:64]^T emb[n] + b1 + fied[n]*W1[128]
//   v[n] = W1[64:128]^T emb[n] + fied[n]*W1[129]
// fp16 storage for u,v (packed v_pk_add_f16 + mfma *_f16 path).
// K1: u,v via transposed MFMA GEMM (A=W1^T, B=emb^T) -> lane holds one
//     node's contiguous features -> half4 (8B) vector stores.
// K2: per 16-edge tile/wave, depth-2 software pipeline (16 gather loads in
//     flight/wave), h2^T = W2^T.h1^T via mfma, fused layer-3, 2-hop shfl
//     reduce, coalesced store. Gather-bound kernel: MLP is the currency.

#define HD 64

typedef __attribute__((ext_vector_type(8))) _Float16 half8;
typedef __attribute__((ext_vector_type(4))) _Float16 half4;
typedef __attribute__((ext_vector_type(8))) short  short8;
typedef __attribute__((ext_vector_type(8))) float  float8;
typedef __attribute__((ext_vector_type(4))) float  f32x4;

__device__ __forceinline__ half8 relu_h8(half8 x) {
    short8 b = __builtin_bit_cast(short8, x);
    short8 m = b >> 15;
    b = b & ~m;
    return __builtin_bit_cast(half8, b);
}

// ---------------- K1: u,v precompute, transposed MFMA GEMM ----------------
// D = W1^T . emb^T : A[m][k] = W1[k][t*16+m], B[k][n] = emb[n0+n][k].
// D layout: col = c = node-in-tile, row = q*4+r = feature t*16+q*4+r.
__global__ __launch_bounds__(256) void precompute_uv(
    const float* __restrict__ emb, const float* __restrict__ fied,
    const float* __restrict__ W1, const float* __restrict__ b1,
    _Float16* __restrict__ u, _Float16* __restrict__ v,
    int n_nodes, int ntiles)
{
    const int lane = threadIdx.x & 63;
    const int q = lane >> 4;
    const int c = lane & 15;
    const int wid = blockIdx.x * (blockDim.x >> 6) + (threadIdx.x >> 6);
    const int nw  = gridDim.x * (blockDim.x >> 6);

    // A fragments for u (W1 rows 0..63) and v (rows 64..127)
    half8 Au[4][2], Av[4][2];
    #pragma unroll
    for (int t = 0; t < 4; ++t)
        #pragma unroll
        for (int ks = 0; ks < 2; ++ks)
            #pragma unroll
            for (int j = 0; j < 8; ++j) {
                int k = ks * 32 + q * 8 + j;
                Au[t][ks][j] = (_Float16)W1[k * HD + t * 16 + c];
                Av[t][ks][j] = (_Float16)W1[(64 + k) * HD + t * 16 + c];
            }
    // epilogue consts for features f = t*16 + q*4 + (0..3)
    f32x4 b1q[4], wsq[4], wdq[4];
    #pragma unroll
    for (int t = 0; t < 4; ++t) {
        b1q[t] = *(const f32x4*)(b1 + t * 16 + q * 4);
        wsq[t] = *(const f32x4*)(W1 + 128 * HD + t * 16 + q * 4);
        wdq[t] = *(const f32x4*)(W1 + 129 * HD + t * 16 + q * 4);
    }

    for (int tile = wid; tile < ntiles; tile += nw) {
        const int n0 = tile * 16;
        const int n  = n0 + c;
        int na = n; if (na >= n_nodes) na = n_nodes - 1;   // clamp, stores guarded
        const float* rp = emb + (size_t)na * HD + q * 8;
        float8 a0 = *(const float8*)rp;
        float8 a1 = *(const float8*)(rp + 32);
        half8 B0 = __builtin_convertvector(a0, half8);
        half8 B1 = __builtin_convertvector(a1, half8);

        f32x4 aU[4] = {}, aV[4] = {};
        #pragma unroll
        for (int t = 0; t < 4; ++t) {
            aU[t] = __builtin_amdgcn_mfma_f32_16x16x32_f16(Au[t][0], B0, aU[t], 0, 0, 0);
            aU[t] = __builtin_amdgcn_mfma_f32_16x16x32_f16(Au[t][1], B1, aU[t], 0, 0, 0);
            aV[t] = __builtin_amdgcn_mfma_f32_16x16x32_f16(Av[t][0], B0, aV[t], 0, 0, 0);
            aV[t] = __builtin_amdgcn_mfma_f32_16x16x32_f16(Av[t][1], B1, aV[t], 0, 0, 0);
        }

        const float fv = fied[na];
        const bool ok = (n < n_nodes);
        #pragma unroll
        for (int t = 0; t < 4; ++t) {
            half4 hu, hv;
            #pragma unroll
            for (int r = 0; r < 4; ++r) {
                hu[r] = (_Float16)(aU[t][r] + b1q[t][r] + fv * wsq[t][r]);
                hv[r] = (_Float16)(aV[t][r] + fv * wdq[t][r]);
            }
            if (ok) {
                *(half4*)(u + (size_t)n * HD + t * 16 + q * 4) = hu;
                *(half4*)(v + (size_t)n * HD + t * 16 + q * 4) = hv;
            }
        }
    }
}

// ---------------- K2: per-edge MLP (layers 2+3), depth-2 pipeline ---------
// D' = W2^T . h1^T : A = W2^T (preloaded), B = h1^T (gathered).
// D' layout: col = c = edge, row = q*4+r = feature t*16+q*4+r.
__global__ __launch_bounds__(256) void edge_mlp(
    const _Float16* __restrict__ u, const _Float16* __restrict__ v,
    const int* __restrict__ src, const int* __restrict__ dst,
    const float* __restrict__ W2, const float* __restrict__ b2,
    const float* __restrict__ W3, const float* __restrict__ b3,
    float* __restrict__ out, int E, int ntiles)
{
    const int lane = threadIdx.x & 63;
    const int q = lane >> 4;
    const int c = lane & 15;
    const int wid = blockIdx.x * (blockDim.x >> 6) + (threadIdx.x >> 6);
    const int nw  = gridDim.x * (blockDim.x >> 6);

    half8 Af[4][2];
    #pragma unroll
    for (int t = 0; t < 4; ++t)
        #pragma unroll
        for (int ks = 0; ks < 2; ++ks)
            #pragma unroll
            for (int j = 0; j < 8; ++j) {
                int k = ks * 32 + q * 8 + j;
                Af[t][ks][j] = (_Float16)W2[k * HD + t * 16 + c];
            }
    f32x4 b2q[4], w3q[4];
    #pragma unroll
    for (int t = 0; t < 4; ++t) {
        b2q[t] = *(const f32x4*)(b2 + t * 16 + q * 4);
        w3q[t] = *(const f32x4*)(W3 + t * 16 + q * 4);
    }
    const float b3v = b3[0];

    const int stride = nw * 2;
    int base = wid * 2;

    half8 U0a, U0b, V0a, V0b, U1a, U1b, V1a, V1b;

    auto load_idx = [&](int tile, int& s, int& d) {
        int e = tile * 16 + c; if (e >= E) e = E - 1;
        s = src[e]; d = dst[e];
    };
    auto issue = [&](int s, int d, half8& Ua, half8& Ub, half8& Va, half8& Vb) {
        const half8* up = (const half8*)(u + (unsigned)s * HD + q * 8);
        const half8* vp = (const half8*)(v + (unsigned)d * HD + q * 8);
        Ua = up[0]; Ub = up[4]; Va = vp[0]; Vb = vp[4];
    };
    auto compute_store = [&](int tile, half8 Ua, half8 Ub, half8 Va, half8 Vb) {
        half8 B0 = relu_h8(Ua + Va);
        half8 B1 = relu_h8(Ub + Vb);
        f32x4 acc[4] = {};
        #pragma unroll
        for (int t = 0; t < 4; ++t) {
            acc[t] = __builtin_amdgcn_mfma_f32_16x16x32_f16(Af[t][0], B0, acc[t], 0, 0, 0);
            acc[t] = __builtin_amdgcn_mfma_f32_16x16x32_f16(Af[t][1], B1, acc[t], 0, 0, 0);
        }
        float p = 0.f;
        #pragma unroll
        for (int t = 0; t < 4; ++t)
            #pragma unroll
            for (int r = 0; r < 4; ++r)
                p = fmaf(fmaxf(acc[t][r] + b2q[t][r], 0.f), w3q[t][r], p);
        p += __shfl_xor(p, 16, 64);
        p += __shfl_xor(p, 32, 64);
        if (q == 0) {
            int e = tile * 16 + c;
            if (e < E) out[e] = p + b3v;
        }
    };

    if (base < ntiles) {
        int s, d; load_idx(base, s, d);
        issue(s, d, U0a, U0b, V0a, V0b);
    }
    if (base + 1 < ntiles) {
        int s, d; load_idx(base + 1, s, d);
        issue(s, d, U1a, U1b, V1a, V1b);
    }

    for (; base < ntiles; base += stride) {
        const int nb = base + stride;
        const bool h2 = (nb < ntiles), h3 = (nb + 1 < ntiles);
        int s2 = 0, d2 = 0, s3 = 0, d3 = 0;
        if (h2) load_idx(nb, s2, d2);
        if (h3) load_idx(nb + 1, s3, d3);

        compute_store(base, U0a, U0b, V0a, V0b);       // consumes G0 (G1 in flight)
        if (h2) issue(s2, d2, U0a, U0b, V0a, V0b);     // refill G0

        if (base + 1 < ntiles)
            compute_store(base + 1, U1a, U1b, V1a, V1b); // consumes G1 (G0' in flight)
        if (h3) issue(s3, d3, U1a, U1b, V1a, V1b);     // refill G1
    }
}

extern "C" void kernel_launch(void* const* d_in, const int* in_sizes, int n_in,
                              void* d_out, int out_size, void* d_ws, size_t ws_size,
                              hipStream_t stream) {
    const float* emb  = (const float*)d_in[0];
    const float* fied = (const float*)d_in[1];
    const float* W1   = (const float*)d_in[2];
    const float* b1   = (const float*)d_in[3];
    const float* W2   = (const float*)d_in[4];
    const float* b2   = (const float*)d_in[5];
    const float* W3   = (const float*)d_in[6];
    const float* b3   = (const float*)d_in[7];
    const int*   eidx = (const int*)d_in[8];

    const int n_nodes = in_sizes[1];
    const int E       = in_sizes[8] / 2;
    const int* srcp = eidx;
    const int* dstp = eidx + E;

    _Float16* u = (_Float16*)d_ws;                 // n_nodes*64 fp16
    _Float16* v = u + (size_t)n_nodes * HD;        // n_nodes*64 fp16

    const int ntilesN = (n_nodes + 15) / 16;
    precompute_uv<<<512, 256, 0, stream>>>(emb, fied, W1, b1, u, v,
                                           n_nodes, ntilesN);

    const int ntilesE = (E + 15) / 16;
    edge_mlp<<<2048, 256, 0, stream>>>(u, v, srcp, dstp, W2, b2, W3, b3,
                                       (float*)d_out, E, ntilesE);
}

// Round 4
// 176.382 us; speedup vs baseline: 1.4327x; 1.0306x over previous
//
#include <hip/hip_runtime.h>

// SpectralRewiringLayer. Factorized: h1 = relu(u[src] + v[dst]),
//   u[n] = W1[0:64]^T emb[n] + b1 + fied[n]*W1[128]
//   v[n] = W1[64:128]^T emb[n] + fied[n]*W1[129]
// fp16 storage for u,v (packed v_pk_add_f16 + mfma *_f16 path).
// K1: u,v via transposed MFMA GEMM (A=W1^T, B=emb^T), half4 stores.
// K2: per 16-edge tile/wave, depth-2 gather pipeline with indices prefetched
//     ONE FULL ITERATION AHEAD. vmcnt retires in issue order, so using
//     same-iteration index loads to form gather addresses forces a full
//     drain (R3 bug). With idx_cur/idx_next decoupled, every wait only
//     covers ops older than the consumed data.

#define HD 64

typedef __attribute__((ext_vector_type(8))) _Float16 half8;
typedef __attribute__((ext_vector_type(4))) _Float16 half4;
typedef __attribute__((ext_vector_type(8))) short  short8;
typedef __attribute__((ext_vector_type(8))) float  float8;
typedef __attribute__((ext_vector_type(4))) float  f32x4;

__device__ __forceinline__ half8 relu_h8(half8 x) {
    short8 b = __builtin_bit_cast(short8, x);
    short8 m = b >> 15;
    b = b & ~m;
    return __builtin_bit_cast(half8, b);
}

// ---------------- K1: u,v precompute, transposed MFMA GEMM ----------------
__global__ __launch_bounds__(256) void precompute_uv(
    const float* __restrict__ emb, const float* __restrict__ fied,
    const float* __restrict__ W1, const float* __restrict__ b1,
    _Float16* __restrict__ u, _Float16* __restrict__ v,
    int n_nodes, int ntiles)
{
    const int lane = threadIdx.x & 63;
    const int q = lane >> 4;
    const int c = lane & 15;
    const int wid = blockIdx.x * (blockDim.x >> 6) + (threadIdx.x >> 6);
    const int nw  = gridDim.x * (blockDim.x >> 6);

    half8 Au[4][2], Av[4][2];
    #pragma unroll
    for (int t = 0; t < 4; ++t)
        #pragma unroll
        for (int ks = 0; ks < 2; ++ks)
            #pragma unroll
            for (int j = 0; j < 8; ++j) {
                int k = ks * 32 + q * 8 + j;
                Au[t][ks][j] = (_Float16)W1[k * HD + t * 16 + c];
                Av[t][ks][j] = (_Float16)W1[(64 + k) * HD + t * 16 + c];
            }
    f32x4 b1q[4], wsq[4], wdq[4];
    #pragma unroll
    for (int t = 0; t < 4; ++t) {
        b1q[t] = *(const f32x4*)(b1 + t * 16 + q * 4);
        wsq[t] = *(const f32x4*)(W1 + 128 * HD + t * 16 + q * 4);
        wdq[t] = *(const f32x4*)(W1 + 129 * HD + t * 16 + q * 4);
    }

    for (int tile = wid; tile < ntiles; tile += nw) {
        const int n0 = tile * 16;
        const int n  = n0 + c;
        int na = n; if (na >= n_nodes) na = n_nodes - 1;
        const float* rp = emb + (size_t)na * HD + q * 8;
        float8 a0 = *(const float8*)rp;
        float8 a1 = *(const float8*)(rp + 32);
        half8 B0 = __builtin_convertvector(a0, half8);
        half8 B1 = __builtin_convertvector(a1, half8);

        f32x4 aU[4] = {}, aV[4] = {};
        #pragma unroll
        for (int t = 0; t < 4; ++t) {
            aU[t] = __builtin_amdgcn_mfma_f32_16x16x32_f16(Au[t][0], B0, aU[t], 0, 0, 0);
            aU[t] = __builtin_amdgcn_mfma_f32_16x16x32_f16(Au[t][1], B1, aU[t], 0, 0, 0);
            aV[t] = __builtin_amdgcn_mfma_f32_16x16x32_f16(Av[t][0], B0, aV[t], 0, 0, 0);
            aV[t] = __builtin_amdgcn_mfma_f32_16x16x32_f16(Av[t][1], B1, aV[t], 0, 0, 0);
        }

        const float fv = fied[na];
        const bool ok = (n < n_nodes);
        #pragma unroll
        for (int t = 0; t < 4; ++t) {
            half4 hu, hv;
            #pragma unroll
            for (int r = 0; r < 4; ++r) {
                hu[r] = (_Float16)(aU[t][r] + b1q[t][r] + fv * wsq[t][r]);
                hv[r] = (_Float16)(aV[t][r] + fv * wdq[t][r]);
            }
            if (ok) {
                *(half4*)(u + (size_t)n * HD + t * 16 + q * 4) = hu;
                *(half4*)(v + (size_t)n * HD + t * 16 + q * 4) = hv;
            }
        }
    }
}

// ---------------- K2: per-edge MLP (layers 2+3) ----------------
// D' = W2^T . h1^T : A = W2^T (preloaded), B = h1^T (gathered).
// D' layout: col = c = edge, row = q*4+r = feature t*16+q*4+r.
__global__ __launch_bounds__(256) void edge_mlp(
    const _Float16* __restrict__ u, const _Float16* __restrict__ v,
    const int* __restrict__ src, const int* __restrict__ dst,
    const float* __restrict__ W2, const float* __restrict__ b2,
    const float* __restrict__ W3, const float* __restrict__ b3,
    float* __restrict__ out, int E, int ntiles)
{
    const int lane = threadIdx.x & 63;
    const int q = lane >> 4;
    const int c = lane & 15;
    const int wid = blockIdx.x * (blockDim.x >> 6) + (threadIdx.x >> 6);
    const int nw  = gridDim.x * (blockDim.x >> 6);

    half8 Af[4][2];
    #pragma unroll
    for (int t = 0; t < 4; ++t)
        #pragma unroll
        for (int ks = 0; ks < 2; ++ks)
            #pragma unroll
            for (int j = 0; j < 8; ++j) {
                int k = ks * 32 + q * 8 + j;
                Af[t][ks][j] = (_Float16)W2[k * HD + t * 16 + c];
            }
    f32x4 b2q[4], w3q[4];
    #pragma unroll
    for (int t = 0; t < 4; ++t) {
        b2q[t] = *(const f32x4*)(b2 + t * 16 + q * 4);
        w3q[t] = *(const f32x4*)(W3 + t * 16 + q * 4);
    }
    const float b3v = b3[0];

    const int stride = nw * 2;
    const int base0  = wid * 2;

    // clamped edge id for a tile (always-valid loads; stores guarded)
    auto eid = [&](int tile) {
        int t = tile; if (t >= ntiles) t = ntiles - 1;
        int e = t * 16 + c; if (e >= E) e = E - 1;
        return e;
    };
    auto issue = [&](int s, int d, half8& Ua, half8& Ub, half8& Va, half8& Vb) {
        const half8* up = (const half8*)(u + (unsigned)s * HD + q * 8);
        const half8* vp = (const half8*)(v + (unsigned)d * HD + q * 8);
        Ua = up[0]; Ub = up[4]; Va = vp[0]; Vb = vp[4];
    };
    auto compute_store = [&](int tile, half8 Ua, half8 Ub, half8 Va, half8 Vb) {
        half8 B0 = relu_h8(Ua + Va);
        half8 B1 = relu_h8(Ub + Vb);
        f32x4 acc[4] = {};
        #pragma unroll
        for (int t = 0; t < 4; ++t) {
            acc[t] = __builtin_amdgcn_mfma_f32_16x16x32_f16(Af[t][0], B0, acc[t], 0, 0, 0);
            acc[t] = __builtin_amdgcn_mfma_f32_16x16x32_f16(Af[t][1], B1, acc[t], 0, 0, 0);
        }
        float p = 0.f;
        #pragma unroll
        for (int t = 0; t < 4; ++t)
            #pragma unroll
            for (int r = 0; r < 4; ++r)
                p = fmaf(fmaxf(acc[t][r] + b2q[t][r], 0.f), w3q[t][r], p);
        p += __shfl_xor(p, 16, 64);
        p += __shfl_xor(p, 32, 64);
        if (q == 0) {
            int e = tile * 16 + c;
            if (e < E) out[e] = p + b3v;
        }
    };

    if (base0 >= ntiles) return;

    // ---- prologue ----
    // idx stage 0: indices for tiles (base0, base0+1)
    int e0 = eid(base0), e1 = eid(base0 + 1);
    int s0 = src[e0], d0 = dst[e0];
    int s1 = src[e1], d1 = dst[e1];
    half8 U0a, U0b, V0a, V0b, U1a, U1b, V1a, V1b;
    issue(s0, d0, U0a, U0b, V0a, V0b);            // G0(base0)
    issue(s1, d1, U1a, U1b, V1a, V1b);            // G1(base0+1)
    // idx_cur: indices for tiles (base0+stride, +1) — used to REFILL next iter
    int e2 = eid(base0 + stride), e3 = eid(base0 + stride + 1);
    int sc0 = src[e2], dc0 = dst[e2];
    int sc1 = src[e3], dc1 = dst[e3];

    for (int base = base0; base < ntiles; base += stride) {
        // idx_next: indices for tiles two strides out (consumed NEXT iter)
        const int f0 = eid(base + 2 * stride), f1 = eid(base + 2 * stride + 1);
        const int sn0 = src[f0], dn0 = dst[f0];
        const int sn1 = src[f1], dn1 = dst[f1];

        // consume G0 (oldest vmem) — G1, refills, idx_next stay in flight
        compute_store(base, U0a, U0b, V0a, V0b);
        issue(sc0, dc0, U0a, U0b, V0a, V0b);      // refill G0 (idx_cur: retired long ago)

        compute_store(base + 1, U1a, U1b, V1a, V1b);
        issue(sc1, dc1, U1a, U1b, V1a, V1b);      // refill G1

        sc0 = sn0; dc0 = dn0; sc1 = sn1; dc1 = dn1;   // rotate idx pipeline
    }
}

extern "C" void kernel_launch(void* const* d_in, const int* in_sizes, int n_in,
                              void* d_out, int out_size, void* d_ws, size_t ws_size,
                              hipStream_t stream) {
    const float* emb  = (const float*)d_in[0];
    const float* fied = (const float*)d_in[1];
    const float* W1   = (const float*)d_in[2];
    const float* b1   = (const float*)d_in[3];
    const float* W2   = (const float*)d_in[4];
    const float* b2   = (const float*)d_in[5];
    const float* W3   = (const float*)d_in[6];
    const float* b3   = (const float*)d_in[7];
    const int*   eidx = (const int*)d_in[8];

    const int n_nodes = in_sizes[1];
    const int E       = in_sizes[8] / 2;
    const int* srcp = eidx;
    const int* dstp = eidx + E;

    _Float16* u = (_Float16*)d_ws;                 // n_nodes*64 fp16
    _Float16* v = u + (size_t)n_nodes * HD;        // n_nodes*64 fp16

    const int ntilesN = (n_nodes + 15) / 16;
    precompute_uv<<<1024, 256, 0, stream>>>(emb, fied, W1, b1, u, v,
                                            n_nodes, ntilesN);

    const int ntilesE = (E + 15) / 16;
    edge_mlp<<<2048, 256, 0, stream>>>(u, v, srcp, dstp, W2, b2, W3, b3,
                                       (float*)d_out, E, ntilesE);
}